// Round 9
// baseline (233.784 us; speedup 1.0000x reference)
//
#include <hip/hip_runtime.h>
#include <hip/hip_bf16.h>
#include <stdint.h>

typedef __bf16 bf16;
typedef bf16 bf16x4 __attribute__((ext_vector_type(4)));
typedef bf16 bf16x8 __attribute__((ext_vector_type(8)));
typedef float f32x4 __attribute__((ext_vector_type(4)));

#define LOGSQRT2PI 0.9189385332046727f

__device__ __forceinline__ void gload_lds16(const void* g, void* l) {
    __builtin_amdgcn_global_load_lds((__attribute__((address_space(1))) void*)g,
                                     (__attribute__((address_space(3))) void*)l,
                                     16, 0, 0);
}

// ---- merged weight prep (proven r6): W = mu+(1e-6+softplus(p))*eps ;
// ---- Wt[n][k] bf16 ; lqw/lpw atomics ----
__device__ __forceinline__ void prep_body(const float* __restrict__ mu,
        const float* __restrict__ p, const float* __restrict__ eps,
        bf16* __restrict__ Wt, int N, int Npad, float* __restrict__ osc,
        int vb, int nblocks) {
    int total = 512 * Npad;
    float lqw = 0.f, lpw = 0.f;
    for (int idx = vb * 256 + threadIdx.x; idx < total; idx += nblocks * 256) {
        int k = idx / Npad, n = idx - k * Npad;
        float w = 0.f;
        if (n < N) {
            int src = k * N + n;
            float m = mu[src], e = eps[src];
            float sd = 1e-6f + log1pf(expf(p[src]));
            w = m + sd * e;
            float z = (w - m) / sd;
            lqw += -LOGSQRT2PI - logf(sd) - 0.5f * z * z;
            lpw += -LOGSQRT2PI - 0.5f * w * w;
        }
        Wt[n * 512 + k] = (bf16)w;
    }
    #pragma unroll
    for (int off = 32; off; off >>= 1) {
        lqw += __shfl_down(lqw, off);
        lpw += __shfl_down(lpw, off);
    }
    if ((threadIdx.x & 63) == 0) {
        atomicAdd(&osc[0], lqw);
        atomicAdd(&osc[1], lpw);
    }
}

__global__ void k_prep_all(const float* __restrict__ mu1, const float* __restrict__ p1,
                           const float* __restrict__ e1,
                           const float* __restrict__ mu2, const float* __restrict__ p2,
                           const float* __restrict__ e2,
                           const float* __restrict__ mu3, const float* __restrict__ p3,
                           const float* __restrict__ e3,
                           bf16* __restrict__ Wt1, bf16* __restrict__ Wt2,
                           bf16* __restrict__ Wt3, float* __restrict__ osc) {
    int b = blockIdx.x;
    if (b < 256)      prep_body(mu1, p1, e1, Wt1, 512, 512, osc, b, 256);
    else if (b < 512) prep_body(mu2, p2, e2, Wt2, 512, 512, osc, b - 256, 256);
    else              prep_body(mu3, p3, e3, Wt3, 10,  16,  osc, b - 512, 16);
}

// ---- x fp32 -> bf16 ----
__global__ void k_cvt(const float4* __restrict__ in, bf16x4* __restrict__ out, int n4) {
    int stride = gridDim.x * blockDim.x;
    for (int i = blockIdx.x * blockDim.x + threadIdx.x; i < n4; i += stride) {
        float4 v = in[i];
        bf16x4 o;
        o[0] = (bf16)v.x; o[1] = (bf16)v.y; o[2] = (bf16)v.z; o[3] = (bf16)v.w;
        out[i] = o;
    }
}

// ============================================================================
// 128x128 tile, BK=32, 4 waves (2Mx2N), TRIPLE-buffered LDS (3 x 16 KB), ONE
// barrier + 16 MFMA per K-iter, prefetch distance 2 iters, counted vmcnt(4).
// 48 KB LDS + ~115 VGPR -> 3 blocks/CU = 12 drifting waves/CU.
//
// LDS buf = 16 chunks x 1 KB (A rg0-7, B rg0-7), fragment-ordered: chunk rg,
// lane l holds M[rg*16 + (l&15)][kt*32 + (l>>4)*8 ..+8] at chunk + l*8 ->
// wave frag read = contiguous 1 KB ds_read_b128, conflict-free (r4-proven).
// STG(t): wave w stages chunks {w, 4+w, 8+w, 12+w} = 4 gloads/thread = batch 4.
// Gate: at end of iter t only stage(t+2) (4 loads) may remain -> vmcnt(4);
// tail t==14 -> vmcnt(0).  Buffers t%3, (t+1)%3, (t+2)%3 pairwise distinct.
// ============================================================================
template<bool FUSE3>
__global__ __launch_bounds__(256, 3)
void k_gemm(const bf16* __restrict__ A, const bf16* __restrict__ Bt,
            bf16* __restrict__ C, const bf16* __restrict__ W3t,
            float* __restrict__ Y) {
    __shared__ __align__(16) bf16 L[24576];   // 48 KB
    const int tid = threadIdx.x;
    const int l = tid & 63, w = tid >> 6;
    const int wm = w >> 1, wn = w & 1;
    const int l8 = l * 8;

    // bijective XCD swizzle (2048 % 8 == 0): the 4 bn-tiles of each bm share an XCD
    const int bid = blockIdx.x;
    const int logical = (bid & 7) * 256 + (bid >> 3);
    const long bm = (long)(logical >> 2) * 128;
    const int  bn = (logical & 3) * 128;

    const bf16* Asrc = A  + (bm + (l & 15)) * 512 + ((l >> 4) * 8);
    const bf16* Bsrc = Bt + ((long)bn + (l & 15)) * 512 + ((l >> 4) * 8);

    #define STG(KT, BUF) do {                                                  \
        gload_lds16(Asrc + (w)     * (16 * 512) + (KT) * 32,                   \
                    &L[(BUF) * 8192 + (w) * 512 + l8]);                        \
        gload_lds16(Asrc + (4 + w) * (16 * 512) + (KT) * 32,                   \
                    &L[(BUF) * 8192 + (4 + w) * 512 + l8]);                    \
        gload_lds16(Bsrc + (w)     * (16 * 512) + (KT) * 32,                   \
                    &L[(BUF) * 8192 + (8 + w) * 512 + l8]);                    \
        gload_lds16(Bsrc + (4 + w) * (16 * 512) + (KT) * 32,                   \
                    &L[(BUF) * 8192 + (12 + w) * 512 + l8]);                   \
    } while (0)

    f32x4 acc[4][4];
    #pragma unroll
    for (int i = 0; i < 4; i++)
        #pragma unroll
        for (int j = 0; j < 4; j++) acc[i][j] = (f32x4){0.f, 0.f, 0.f, 0.f};
    bf16x8 afr[4], bfr[4];

    // prologue: 2 tiles in flight
    STG(0, 0);
    STG(1, 1);
    asm volatile("s_waitcnt vmcnt(4)" ::: "memory");   // tile0 landed
    __builtin_amdgcn_s_barrier();

    for (int t = 0; t < 16; ++t) {
        const int buf = t % 3;
        if (t < 14) STG(t + 2, (t + 2) % 3);           // prefetch 2 ahead
        #pragma unroll
        for (int i = 0; i < 4; i++)
            afr[i] = *(const bf16x8*)&L[buf * 8192 + (wm * 4 + i) * 512 + l8];
        #pragma unroll
        for (int j = 0; j < 4; j++)
            bfr[j] = *(const bf16x8*)&L[buf * 8192 + (8 + wn * 4 + j) * 512 + l8];
        #pragma unroll
        for (int i = 0; i < 4; i++)
            #pragma unroll
            for (int j = 0; j < 4; j++)
                acc[i][j] = __builtin_amdgcn_mfma_f32_16x16x32_bf16(
                    afr[i], bfr[j], acc[i][j], 0, 0, 0);
        if (t < 14)       { asm volatile("s_waitcnt vmcnt(4)" ::: "memory"); }
        else if (t == 14) { asm volatile("s_waitcnt vmcnt(0)" ::: "memory"); }
        __builtin_amdgcn_s_barrier();                  // one barrier per iter
    }

    // ---- epilogue (r4-proven): acc -> LDS [128][128] bf16, ReLU, 16B-chunk
    // swizzle phys_chunk = cc ^ (row&7) ----
    #pragma unroll
    for (int i = 0; i < 4; i++)
        #pragma unroll
        for (int j = 0; j < 4; j++)
            #pragma unroll
            for (int q = 0; q < 4; q++) {
                int row = wm * 64 + i * 16 + (l >> 4) * 4 + q;
                int col = wn * 64 + j * 16 + (l & 15);
                float v = fmaxf(acc[i][j][q], 0.f);
                L[row * 128 + ((col >> 3) ^ (row & 7)) * 8 + (col & 7)] = (bf16)v;
            }
    __syncthreads();

    if (!FUSE3) {
        // coalesced dwordx4 stores
        #pragma unroll
        for (int it = 0; it < 8; it++) {
            int row = it * 16 + (tid >> 4);
            int cc = tid & 15;
            bf16x8 v = *(const bf16x8*)&L[row * 128 + ((cc ^ (row & 7)) * 8)];
            *(bf16x8*)(C + (bm + row) * 512 + bn + cc * 8) = v;
        }
    } else {
        // fused layer 3: y[rows][0..9] += h2[rows][bn..bn+127] @ W3t[.][bn..]
        bf16x8 b3[4];
        #pragma unroll
        for (int ks = 0; ks < 4; ks++)
            b3[ks] = *(const bf16x8*)(W3t + (l & 15) * 512 + bn + ks * 32 + (l >> 4) * 8);
        f32x4 yacc[2];
        yacc[0] = (f32x4){0.f, 0.f, 0.f, 0.f};
        yacc[1] = (f32x4){0.f, 0.f, 0.f, 0.f};
        #pragma unroll
        for (int fr = 0; fr < 2; fr++)
            #pragma unroll
            for (int ks = 0; ks < 4; ks++) {
                int row = w * 32 + fr * 16 + (l & 15);
                int cc = ks * 4 + (l >> 4);
                bf16x8 a3 = *(const bf16x8*)&L[row * 128 + ((cc ^ (row & 7)) * 8)];
                yacc[fr] = __builtin_amdgcn_mfma_f32_16x16x32_bf16(a3, b3[ks], yacc[fr], 0, 0, 0);
            }
        if ((l & 15) < 10) {
            #pragma unroll
            for (int fr = 0; fr < 2; fr++)
                #pragma unroll
                for (int q = 0; q < 4; q++) {
                    long row = bm + w * 32 + fr * 16 + (l >> 4) * 4 + q;
                    atomicAdd(Y + row * 10 + (l & 15), yacc[fr][q]);
                }
        }
    }
    #undef STG
}

extern "C" void kernel_launch(void* const* d_in, const int* in_sizes, int n_in,
                              void* d_out, int out_size, void* d_ws, size_t ws_size,
                              hipStream_t stream) {
    const float* x   = (const float*)d_in[0];
    const float* mu1 = (const float*)d_in[1];
    const float* p1  = (const float*)d_in[2];
    const float* e1  = (const float*)d_in[3];
    const float* mu2 = (const float*)d_in[4];
    const float* p2  = (const float*)d_in[5];
    const float* e2  = (const float*)d_in[6];
    const float* mu3 = (const float*)d_in[7];
    const float* p3  = (const float*)d_in[8];
    const float* e3  = (const float*)d_in[9];
    float* out = (float*)d_out;

    const int B = 65536, D = 512, DO = 10;

    char* ws = (char*)d_ws;
    bf16* Wt1 = (bf16*)(ws);
    bf16* Wt2 = (bf16*)(ws + 524288);
    bf16* Wt3 = (bf16*)(ws + 1048576);
    bf16* xb  = (bf16*)(ws + 1114112);
    bf16* h1  = (bf16*)(ws + 1114112 + 67108864);

    float* osc = out + (long)B * DO;

    hipMemsetAsync(out, 0, (size_t)out_size * sizeof(float), stream);
    hipLaunchKernelGGL(k_prep_all, dim3(528), dim3(256), 0, stream,
                       mu1, p1, e1, mu2, p2, e2, mu3, p3, e3, Wt1, Wt2, Wt3, osc);
    hipLaunchKernelGGL(k_cvt, dim3(2048), dim3(256), 0, stream,
                       (const float4*)x, (bf16x4*)xb, B * D / 4);
    hipLaunchKernelGGL((k_gemm<false>), dim3(2048), dim3(256), 0, stream,
                       xb, Wt1, h1, (const bf16*)nullptr, (float*)nullptr);
    hipLaunchKernelGGL((k_gemm<true>), dim3(2048), dim3(256), 0, stream,
                       h1, Wt2, (bf16*)nullptr, Wt3, out);
}